// Round 8
// baseline (794.332 us; speedup 1.0000x reference)
//
#include <hip/hip_runtime.h>
#include <math.h>

#define C 256
#define S 16
#define CR 64
#define NREP 16        // psum replicas (atomic contention /16)

typedef float f4 __attribute__((ext_vector_type(4)));

// ---------------- Kernel 0: histogram of idx (counts per segment) ------------
__global__ __launch_bounds__(256) void k_hist(
    const int* __restrict__ idx, int* __restrict__ pcnt, int nrows)
{
    const int lane = threadIdx.x & 63;
    const int tid  = blockIdx.x * blockDim.x + threadIdx.x;
    const int T    = gridDim.x * blockDim.x;
    const int padded = ((nrows + 63) >> 6) << 6;

    int c0=0,c1=0,c2=0,c3=0,c4=0,c5=0,c6=0,c7=0,
        c8=0,c9=0,c10=0,c11=0,c12=0,c13=0,c14=0,c15=0;

    for (int i = tid; i < padded; i += T) {
        const int v = (i < nrows) ? idx[i] : -1;
        #define CNT(K) c##K += (int)__popcll(__ballot(v == K));
        CNT(0)  CNT(1)  CNT(2)  CNT(3)  CNT(4)  CNT(5)  CNT(6)  CNT(7)
        CNT(8)  CNT(9)  CNT(10) CNT(11) CNT(12) CNT(13) CNT(14) CNT(15)
        #undef CNT
    }
    if (lane == 0) {
        #define FL(K) if (c##K) atomicAdd(&pcnt[K], c##K);
        FL(0)  FL(1)  FL(2)  FL(3)  FL(4)  FL(5)  FL(6)  FL(7)
        FL(8)  FL(9)  FL(10) FL(11) FL(12) FL(13) FL(14) FL(15)
        #undef FL
    }
}

// ---------------- Kernel 1: segment sums — FLAT copy-pattern -----------------
// Thread = one float4 at flat index i (exact float4-copy addressing; wave
// reads 1 KB stride-1). Per-lane segment id (v_cmp/v_cndmask + fmac
// predication, no scalar chain, no branches). Channel-quad of a thread is
// invariant (T % 64 == 0), so accumulators stay channel-consistent.
// Flush: two 8-segment LDS chunks (32 KB) -> one atomic/elem/block.
__global__ __launch_bounds__(256, 4) void k_segsum(
    const float* __restrict__ x, const int* __restrict__ idx,
    float* __restrict__ psum, int nrows)
{
    const int  tid = blockIdx.x * 256 + threadIdx.x;
    const int  T   = gridDim.x * 256;          // multiple of 64 -> quad invariant
    const long n4  = (long)nrows * (C / 4);

    f4 a0={0,0,0,0},a1={0,0,0,0},a2={0,0,0,0},a3={0,0,0,0},
       a4={0,0,0,0},a5={0,0,0,0},a6={0,0,0,0},a7={0,0,0,0},
       a8={0,0,0,0},a9={0,0,0,0},a10={0,0,0,0},a11={0,0,0,0},
       a12={0,0,0,0},a13={0,0,0,0},a14={0,0,0,0},a15={0,0,0,0};

    const f4* __restrict__ x4 = reinterpret_cast<const f4*>(x);

    #define ACC1(K, sv, vv) { const float m = (sv == K) ? 1.0f : 0.0f; \
        a##K.x = fmaf(m, vv.x, a##K.x); a##K.y = fmaf(m, vv.y, a##K.y); \
        a##K.z = fmaf(m, vv.z, a##K.z); a##K.w = fmaf(m, vv.w, a##K.w); }
    #define ROW(sv, vv) \
        ACC1(0,sv,vv)  ACC1(1,sv,vv)  ACC1(2,sv,vv)  ACC1(3,sv,vv) \
        ACC1(4,sv,vv)  ACC1(5,sv,vv)  ACC1(6,sv,vv)  ACC1(7,sv,vv) \
        ACC1(8,sv,vv)  ACC1(9,sv,vv)  ACC1(10,sv,vv) ACC1(11,sv,vv) \
        ACC1(12,sv,vv) ACC1(13,sv,vv) ACC1(14,sv,vv) ACC1(15,sv,vv)

    long i = tid;
    for (; i + T < n4; i += 2L * T) {          // 2 independent chains in flight
        const f4  v0 = x4[i];
        const f4  v1 = x4[i + T];
        const int s0 = idx[i >> 6];            // per-lane; 16 lanes share a word
        const int s1 = idx[(i + T) >> 6];
        ROW(s0, v0)
        ROW(s1, v1)
    }
    for (; i < n4; i += T) {
        const f4  v = x4[i];
        const int s = idx[i >> 6];
        ROW(s, v)
    }
    #undef ROW
    #undef ACC1

    // flush: 32 KB LDS, two 8-segment chunks -> one atomic/elem/block
    __shared__ float red[4][8][C];
    const int w    = threadIdx.x >> 6;
    const int lane = threadIdx.x & 63;
    const int t    = threadIdx.x;
    const int rep  = blockIdx.x & (NREP - 1);
    float* gs = psum + (size_t)rep * S * C;

    #define ST(K, SL) *reinterpret_cast<f4*>(&red[w][SL][4 * lane]) = a##K;
    ST(0,0) ST(1,1) ST(2,2) ST(3,3) ST(4,4) ST(5,5) ST(6,6) ST(7,7)
    __syncthreads();
    #pragma unroll
    for (int s_ = 0; s_ < 8; s_++) {
        const float v = red[0][s_][t] + red[1][s_][t] +
                        red[2][s_][t] + red[3][s_][t];
        atomicAdd(&gs[s_ * C + t], v);
    }
    __syncthreads();
    ST(8,0) ST(9,1) ST(10,2) ST(11,3) ST(12,4) ST(13,5) ST(14,6) ST(15,7)
    __syncthreads();
    #pragma unroll
    for (int s_ = 0; s_ < 8; s_++) {
        const float v = red[0][s_][t] + red[1][s_][t] +
                        red[2][s_][t] + red[3][s_][t];
        atomicAdd(&gs[(8 + s_) * C + t], v);
    }
    #undef ST
}

// ---------------- Kernel 2: reduce replicas + tiny SE MLP ----------------
__global__ __launch_bounds__(256) void k_mlp(
    const float* __restrict__ psum, const int* __restrict__ pcnt,
    const float* __restrict__ w1, const float* __restrict__ w2,
    float* __restrict__ gate)
{
    __shared__ float sm[S][C];
    __shared__ float h[S][CR];
    __shared__ float cnt[S];
    const int t = threadIdx.x;

    if (t < S) cnt[t] = fmaxf((float)pcnt[t], 1.0f);
    __syncthreads();

    for (int i = t; i < S * C; i += 256) {
        float v = 0.0f;
        #pragma unroll
        for (int r = 0; r < NREP; r++) v += psum[r * S * C + i];
        sm[i / C][i % C] = v / cnt[i / C];
    }
    __syncthreads();

    for (int o = t; o < S * CR; o += 256) {
        const int s = o / CR, j = o % CR;
        float acc = 0.0f;
        #pragma unroll 4
        for (int k = 0; k < C; k++) acc += sm[s][k] * w1[k * CR + j];
        h[s][j] = fmaxf(acc, 0.0f);
    }
    __syncthreads();

    for (int o = t; o < S * C; o += 256) {
        const int s = o / C, j = o % C;
        float acc = 0.0f;
        #pragma unroll
        for (int k = 0; k < CR; k++) acc += h[s][k] * w2[k * C + j];
        gate[o] = 1.0f / (1.0f + expf(-acc));
    }
}

// ---------------- Kernel 3: out = x * gate[idx] (exact R1 version) -----------
__global__ __launch_bounds__(256) void k_mod(
    const float* __restrict__ x, const int* __restrict__ idx,
    const float* __restrict__ gate, float* __restrict__ out, int nrows)
{
    const int l    = threadIdx.x & 63;
    const int wrow = threadIdx.x >> 6;
    const float4* __restrict__ x4 = reinterpret_cast<const float4*>(x);
    const float4* __restrict__ g4 = reinterpret_cast<const float4*>(gate);
    float4* __restrict__ o4 = reinterpret_cast<float4*>(out);

    for (int row = blockIdx.x * 4 + wrow; row < nrows; row += gridDim.x * 4) {
        const int s = idx[row];                  // wave-uniform -> broadcast
        float4 v = x4[row * (C / 4) + l];
        const float4 g = g4[s * (C / 4) + l];    // 16 KB table, L1/L2-resident
        v.x *= g.x; v.y *= g.y; v.z *= g.z; v.w *= g.w;
        o4[row * (C / 4) + l] = v;
    }
}

extern "C" void kernel_launch(void* const* d_in, const int* in_sizes, int n_in,
                              void* d_out, int out_size, void* d_ws, size_t ws_size,
                              hipStream_t stream)
{
    const float* x   = (const float*)d_in[0];
    const int*   idx = (const int*)  d_in[1];
    const float* w1  = (const float*)d_in[2];
    const float* w2  = (const float*)d_in[3];
    float* out = (float*)d_out;
    const int nrows = in_sizes[1];

    // ws: [psum: NREP*S*C f32][pcnt: S i32][gate: S*C f32]
    float* psum = (float*)d_ws;
    int*   pcnt = (int*)(psum + NREP * S * C);
    float* gate = (float*)(pcnt + S);

    const size_t zero_bytes = NREP * S * C * sizeof(float) + S * sizeof(int);
    (void)hipMemsetAsync(d_ws, 0, zero_bytes, stream);

    k_hist  <<< 128, 256, 0, stream>>>(idx, pcnt, nrows);
    k_segsum<<<1024, 256, 0, stream>>>(x, idx, psum, nrows);
    k_mlp   <<<   1, 256, 0, stream>>>(psum, pcnt, w1, w2, gate);
    k_mod   <<<2048, 256, 0, stream>>>(x, idx, gate, out, nrows);
}

// Round 9
// 789.461 us; speedup vs baseline: 1.0062x; 1.0062x over previous
//
#include <hip/hip_runtime.h>
#include <math.h>

#define C 256
#define S 16
#define CR 64
#define NREP 16        // psum replicas (atomic contention /16)

typedef float f4 __attribute__((ext_vector_type(4)));

// ---------------- Kernel 0: histogram of idx (counts per segment) ------------
__global__ __launch_bounds__(256) void k_hist(
    const int* __restrict__ idx, int* __restrict__ pcnt, int nrows)
{
    const int lane = threadIdx.x & 63;
    const int tid  = blockIdx.x * blockDim.x + threadIdx.x;
    const int T    = gridDim.x * blockDim.x;
    const int padded = ((nrows + 63) >> 6) << 6;

    int c0=0,c1=0,c2=0,c3=0,c4=0,c5=0,c6=0,c7=0,
        c8=0,c9=0,c10=0,c11=0,c12=0,c13=0,c14=0,c15=0;

    for (int i = tid; i < padded; i += T) {
        const int v = (i < nrows) ? idx[i] : -1;
        #define CNT(K) c##K += (int)__popcll(__ballot(v == K));
        CNT(0)  CNT(1)  CNT(2)  CNT(3)  CNT(4)  CNT(5)  CNT(6)  CNT(7)
        CNT(8)  CNT(9)  CNT(10) CNT(11) CNT(12) CNT(13) CNT(14) CNT(15)
        #undef CNT
    }
    if (lane == 0) {
        #define FL(K) if (c##K) atomicAdd(&pcnt[K], c##K);
        FL(0)  FL(1)  FL(2)  FL(3)  FL(4)  FL(5)  FL(6)  FL(7)
        FL(8)  FL(9)  FL(10) FL(11) FL(12) FL(13) FL(14) FL(15)
        #undef FL
    }
}

// ---------------- Kernel 1: segment sums, pipelined predicated FMAC ----------
// One wave per 64-row superblock; lane owns channels 4l..4l+3 (16 B/lane).
// Scalar masks (readlane idx -> s_cmp/s_cselect -> v_fmac w/ SGPR operand).
// SOFTWARE PIPELINE: 4-row double buffer -- buffer B's loads are issued
// BEFORE computing buffer A, so 4 KB/wave is in flight during every compute
// block (R5/R7 issued-then-drained). Next superblock's idx prefetched too.
__global__ __launch_bounds__(256, 4) void k_segsum(
    const float* __restrict__ x, const int* __restrict__ idx,
    float* __restrict__ psum, int nrows)
{
    const int lane = threadIdx.x & 63;
    const int w    = threadIdx.x >> 6;
    const int gw   = blockIdx.x * 4 + w;
    const int nw   = gridDim.x * 4;

    f4 a0={0,0,0,0},a1={0,0,0,0},a2={0,0,0,0},a3={0,0,0,0},
       a4={0,0,0,0},a5={0,0,0,0},a6={0,0,0,0},a7={0,0,0,0},
       a8={0,0,0,0},a9={0,0,0,0},a10={0,0,0,0},a11={0,0,0,0},
       a12={0,0,0,0},a13={0,0,0,0},a14={0,0,0,0},a15={0,0,0,0};

    const f4* __restrict__ x4 = reinterpret_cast<const f4*>(x);

    #define ACC1(K, sv, vv) { const float m = (sv == K) ? 1.0f : 0.0f; \
        a##K.x = fmaf(m, vv.x, a##K.x); a##K.y = fmaf(m, vv.y, a##K.y); \
        a##K.z = fmaf(m, vv.z, a##K.z); a##K.w = fmaf(m, vv.w, a##K.w); }
    #define ROW(sv, vv) \
        ACC1(0,sv,vv)  ACC1(1,sv,vv)  ACC1(2,sv,vv)  ACC1(3,sv,vv) \
        ACC1(4,sv,vv)  ACC1(5,sv,vv)  ACC1(6,sv,vv)  ACC1(7,sv,vv) \
        ACC1(8,sv,vv)  ACC1(9,sv,vv)  ACC1(10,sv,vv) ACC1(11,sv,vv) \
        ACC1(12,sv,vv) ACC1(13,sv,vv) ACC1(14,sv,vv) ACC1(15,sv,vv)

    // static-index load/compute of a 4-row group at row offset J (0..60)
    #define LOADG(BUF, p, J) { \
        BUF[0] = (p)[(J+0) * (C/4)]; BUF[1] = (p)[(J+1) * (C/4)]; \
        BUF[2] = (p)[(J+2) * (C/4)]; BUF[3] = (p)[(J+3) * (C/4)]; }
    #define COMPG(BUF, vidx, J) { \
        { const int s_ = __builtin_amdgcn_readlane(vidx, J+0); ROW(s_, BUF[0]) } \
        { const int s_ = __builtin_amdgcn_readlane(vidx, J+1); ROW(s_, BUF[1]) } \
        { const int s_ = __builtin_amdgcn_readlane(vidx, J+2); ROW(s_, BUF[2]) } \
        { const int s_ = __builtin_amdgcn_readlane(vidx, J+3); ROW(s_, BUF[3]) } }

    const int nsb = nrows >> 6;
    int vidx = (gw < nsb) ? idx[(gw << 6) + lane] : 0;   // current superblock idx
    for (int sb = gw; sb < nsb; sb += nw) {
        const int row0 = sb << 6;
        const f4* __restrict__ p = x4 + (size_t)row0 * (C/4) + lane;
        const int sbn = sb + nw;
        int vidx_n = vidx;
        if (sbn < nsb) vidx_n = idx[(sbn << 6) + lane];  // prefetch next idx

        f4 A[4], B[4];
        LOADG(A, p, 0)
        LOADG(B, p, 4)   COMPG(A, vidx, 0)
        LOADG(A, p, 8)   COMPG(B, vidx, 4)
        LOADG(B, p, 12)  COMPG(A, vidx, 8)
        LOADG(A, p, 16)  COMPG(B, vidx, 12)
        LOADG(B, p, 20)  COMPG(A, vidx, 16)
        LOADG(A, p, 24)  COMPG(B, vidx, 20)
        LOADG(B, p, 28)  COMPG(A, vidx, 24)
        LOADG(A, p, 32)  COMPG(B, vidx, 28)
        LOADG(B, p, 36)  COMPG(A, vidx, 32)
        LOADG(A, p, 40)  COMPG(B, vidx, 36)
        LOADG(B, p, 44)  COMPG(A, vidx, 40)
        LOADG(A, p, 48)  COMPG(B, vidx, 44)
        LOADG(B, p, 52)  COMPG(A, vidx, 48)
        LOADG(A, p, 56)  COMPG(B, vidx, 52)
        LOADG(B, p, 60)  COMPG(A, vidx, 56)
        COMPG(B, vidx, 60)
        vidx = vidx_n;
    }
    if (gw == 0) {                                     // tail (none if %64==0)
        for (int r = nsb << 6; r < nrows; ++r) {
            const int sv = __builtin_amdgcn_readfirstlane(idx[r]);
            const f4 vv = x4[(size_t)r * (C/4) + lane];
            ROW(sv, vv)
        }
    }
    #undef LOADG
    #undef COMPG
    #undef ROW
    #undef ACC1

    // flush: 32 KB LDS, two 8-segment chunks -> one atomic/elem/block
    __shared__ float red[4][8][C];
    const int t   = threadIdx.x;
    const int rep = blockIdx.x & (NREP - 1);
    float* gs = psum + (size_t)rep * S * C;

    #define ST(K, SL) *reinterpret_cast<f4*>(&red[w][SL][4 * lane]) = a##K;
    ST(0,0) ST(1,1) ST(2,2) ST(3,3) ST(4,4) ST(5,5) ST(6,6) ST(7,7)
    __syncthreads();
    #pragma unroll
    for (int s_ = 0; s_ < 8; s_++) {
        const float v = red[0][s_][t] + red[1][s_][t] +
                        red[2][s_][t] + red[3][s_][t];
        atomicAdd(&gs[s_ * C + t], v);
    }
    __syncthreads();
    ST(8,0) ST(9,1) ST(10,2) ST(11,3) ST(12,4) ST(13,5) ST(14,6) ST(15,7)
    __syncthreads();
    #pragma unroll
    for (int s_ = 0; s_ < 8; s_++) {
        const float v = red[0][s_][t] + red[1][s_][t] +
                        red[2][s_][t] + red[3][s_][t];
        atomicAdd(&gs[(8 + s_) * C + t], v);
    }
    #undef ST
}

// ---------------- Kernel 2: reduce replicas + tiny SE MLP ----------------
__global__ __launch_bounds__(256) void k_mlp(
    const float* __restrict__ psum, const int* __restrict__ pcnt,
    const float* __restrict__ w1, const float* __restrict__ w2,
    float* __restrict__ gate)
{
    __shared__ float sm[S][C];
    __shared__ float h[S][CR];
    __shared__ float cnt[S];
    const int t = threadIdx.x;

    if (t < S) cnt[t] = fmaxf((float)pcnt[t], 1.0f);
    __syncthreads();

    for (int i = t; i < S * C; i += 256) {
        float v = 0.0f;
        #pragma unroll
        for (int r = 0; r < NREP; r++) v += psum[r * S * C + i];
        sm[i / C][i % C] = v / cnt[i / C];
    }
    __syncthreads();

    for (int o = t; o < S * CR; o += 256) {
        const int s = o / CR, j = o % CR;
        float acc = 0.0f;
        #pragma unroll 4
        for (int k = 0; k < C; k++) acc += sm[s][k] * w1[k * CR + j];
        h[s][j] = fmaxf(acc, 0.0f);
    }
    __syncthreads();

    for (int o = t; o < S * C; o += 256) {
        const int s = o / C, j = o % C;
        float acc = 0.0f;
        #pragma unroll
        for (int k = 0; k < CR; k++) acc += h[s][k] * w2[k * C + j];
        gate[o] = 1.0f / (1.0f + expf(-acc));
    }
}

// ---------------- Kernel 3: out = x * gate[idx] (exact R1 version) -----------
__global__ __launch_bounds__(256) void k_mod(
    const float* __restrict__ x, const int* __restrict__ idx,
    const float* __restrict__ gate, float* __restrict__ out, int nrows)
{
    const int l    = threadIdx.x & 63;
    const int wrow = threadIdx.x >> 6;
    const float4* __restrict__ x4 = reinterpret_cast<const float4*>(x);
    const float4* __restrict__ g4 = reinterpret_cast<const float4*>(gate);
    float4* __restrict__ o4 = reinterpret_cast<float4*>(out);

    for (int row = blockIdx.x * 4 + wrow; row < nrows; row += gridDim.x * 4) {
        const int s = idx[row];                  // wave-uniform -> broadcast
        float4 v = x4[row * (C / 4) + l];
        const float4 g = g4[s * (C / 4) + l];    // 16 KB table, L1/L2-resident
        v.x *= g.x; v.y *= g.y; v.z *= g.z; v.w *= g.w;
        o4[row * (C / 4) + l] = v;
    }
}

extern "C" void kernel_launch(void* const* d_in, const int* in_sizes, int n_in,
                              void* d_out, int out_size, void* d_ws, size_t ws_size,
                              hipStream_t stream)
{
    const float* x   = (const float*)d_in[0];
    const int*   idx = (const int*)  d_in[1];
    const float* w1  = (const float*)d_in[2];
    const float* w2  = (const float*)d_in[3];
    float* out = (float*)d_out;
    const int nrows = in_sizes[1];

    // ws: [psum: NREP*S*C f32][pcnt: S i32][gate: S*C f32]
    float* psum = (float*)d_ws;
    int*   pcnt = (int*)(psum + NREP * S * C);
    float* gate = (float*)(pcnt + S);

    const size_t zero_bytes = NREP * S * C * sizeof(float) + S * sizeof(int);
    (void)hipMemsetAsync(d_ws, 0, zero_bytes, stream);

    k_hist  <<< 128, 256, 0, stream>>>(idx, pcnt, nrows);
    k_segsum<<<1024, 256, 0, stream>>>(x, idx, psum, nrows);
    k_mlp   <<<   1, 256, 0, stream>>>(psum, pcnt, w1, w2, gate);
    k_mod   <<<2048, 256, 0, stream>>>(x, idx, gate, out, nrows);
}